// Round 7
// baseline (206.664 us; speedup 1.0000x reference)
//
#include <hip/hip_runtime.h>

// ---------------------------------------------------------------------------
// R11: R10 with compile fixes.
//  - gemm1: LDS dbuf selected via pointer arithmetic (pointer-ARRAY of LDS
//    addrspacecasts was rejected: "unsupported expression in static init")
//  - launch bounds match LDS-limited occupancy: gemm1 (256,3), gemm2 (256,2)
// Unchanged R10 levers:
//  - prep: activity blocks also emit xbf (bf16 x, 32MB) - they read x anyway
//  - gemm1: A staged via global_load_lds from xbf (no fp32 cvt path);
//           K-loop -> 2-phase double-buffer, ONE __syncthreads per K-step
//  - gemm2: 2-phase double-buffer (64KB LDS) + bijective XCD swizzle
//  - epilogues vectorized (operand-swapped MFMA, float4/ushort4)
// ---------------------------------------------------------------------------

typedef __bf16 bf16x8_t __attribute__((ext_vector_type(8)));
typedef float  f32x4_t  __attribute__((ext_vector_type(4)));
typedef unsigned short u16x4 __attribute__((ext_vector_type(4)));

__device__ inline unsigned short f2bf(float f) {
    __bf16 b = (__bf16)f;
    return __builtin_bit_cast(unsigned short, b);
}

// async stage of 8 rows (wave-uniform row0) from bf16 global, 16 B/lane,
// XOR-swizzled granules: LDS slot gs holds global granule gs ^ (row & 7)
__device__ inline void stage_glds(const unsigned short* gtile, int stride, int row0,
                                  unsigned short* lds, int lane) {
    const int r8 = lane >> 3;
    const int gg = (lane & 7) ^ r8;
    const unsigned short* gp = gtile + (size_t)(row0 + r8) * stride + gg * 8;
    unsigned short* lp = lds + row0 * 64;
    __builtin_amdgcn_global_load_lds((const __attribute__((address_space(1))) void*)gp,
                                     (__attribute__((address_space(3))) void*)lp,
                                     16, 0, 0);
}

__device__ inline bf16x8_t ldsfrag(const unsigned short* Ls, int row, int kb) {
    return *(const bf16x8_t*)(Ls + row * 64 + (((kb >> 3) ^ (row & 7)) * 8));
}

// ---------------- K1: activity + xbf emit + transposes ---------------------
__global__ void fused_prep_kernel(const float* __restrict__ x, const float* __restrict__ Wc,
                                  const float* __restrict__ Wf, float* __restrict__ part,
                                  unsigned short* __restrict__ wct, unsigned short* __restrict__ wft,
                                  unsigned short* __restrict__ xbf) {
    const int b = blockIdx.x;
    const int tid = threadIdx.x;

    if (b < 512) {
        const int chunk = b & 7;
        const int rg = b >> 3;
        const int colf4 = tid & 127;
        const int rsub = tid >> 7;
        const float4* base = (const float4*)x + (size_t)chunk * 128 + colf4;
        unsigned short* xdst = xbf + (size_t)chunk * 512 + colf4 * 4;
        float s = 0.f;
        #pragma unroll 4
        for (int i = 0; i < 32; ++i) {
            int row = rg * 64 + i * 2 + rsub;
            float4 v = base[(size_t)row * 1024];
            s += fabsf(v.x) + fabsf(v.y) + fabsf(v.z) + fabsf(v.w);
            u16x4 hv;
            hv[0] = f2bf(v.x); hv[1] = f2bf(v.y); hv[2] = f2bf(v.z); hv[3] = f2bf(v.w);
            *(u16x4*)(xdst + (size_t)row * 4096) = hv;
        }
        #pragma unroll
        for (int off = 32; off > 0; off >>= 1) s += __shfl_down(s, off, 64);
        __shared__ float wsum[4];
        if ((tid & 63) == 0) wsum[tid >> 6] = s;
        __syncthreads();
        if (tid == 0) part[chunk * 64 + rg] = wsum[0] + wsum[1] + wsum[2] + wsum[3];
        return;
    }

    __shared__ float tile[32][33];
    const int tx = tid & 31, ty = tid >> 5;
    const float* src; unsigned short* dst; int R, C, cb, rb;
    int jj = b - 512;
    if (jj < 4096) {                       // Wf^T: (1024,4096) -> (4096,1024)
        src = Wf; dst = wft; R = 1024; C = 4096;
        cb = (jj & 127) * 32; rb = (jj >> 7) * 32;
    } else {                               // Wc[c]^T for ALL c
        jj -= 4096;
        int c = jj >> 8, t = jj & 255;
        src = Wc + (size_t)c * 262144;
        dst = wct + (size_t)c * 262144;
        R = 512; C = 512;
        cb = (t & 15) * 32; rb = (t >> 4) * 32;
    }
    #pragma unroll
    for (int i = 0; i < 4; ++i)
        tile[ty + i * 8][tx] = src[(size_t)(rb + ty + i * 8) * C + cb + tx];
    __syncthreads();
    {
        const int tx8  = tid & 7;
        const int ty32 = tid >> 3;
        u16x4 hv;
        #pragma unroll
        for (int j = 0; j < 4; ++j) hv[j] = f2bf(tile[tx8 * 4 + j][ty32]);
        *(u16x4*)(dst + (size_t)(cb + ty32) * R + rb + tx8 * 4) = hv;
    }
}

// ---------------- K2: GEMM1 — glds A+B, 2-phase double-buffer --------------
__global__ __launch_bounds__(256, 3)
void gemm1_kernel(const unsigned short* __restrict__ xbf, const unsigned short* __restrict__ wct,
                  const float* __restrict__ bc, const float* __restrict__ part,
                  unsigned short* __restrict__ h) {
    // dbuf layout in one raw LDS block (pointer ARITHMETIC only — a local
    // array of LDS pointers triggers an unsupported static initializer):
    //   As buf c @ c*8192 (64x64), Bs buf c @ 16384 + c*16384 (128x64)
    __shared__ __align__(16) unsigned char lds_raw[49152];

    const int tid = threadIdx.x;
    const int wave = tid >> 6;
    const int lane = tid & 63;

    // prologue: reduce part[512] -> act[8] -> top-2 (redundant per block)
    {
        float* sred = (float*)lds_raw;
        sred[tid] = part[tid];
        sred[tid + 256] = part[tid + 256];
        __syncthreads();
        float* act8 = (float*)(lds_raw + 2048);
        if (tid < 8) {
            float a = 0.f;
            #pragma unroll
            for (int k = 0; k < 64; ++k) a += sred[tid * 64 + k];
            act8[tid] = a;
        }
        __syncthreads();
    }
    int sel0, sel1;
    {
        const float* act8 = (const float*)(lds_raw + 2048);
        float v0 = -1e30f, v1 = -1e30f; int b0 = 0, b1 = 0;
        #pragma unroll
        for (int i = 0; i < 8; ++i) {
            float v = act8[i];
            if (v > v0) { v1 = v0; b1 = b0; v0 = v; b0 = i; }
            else if (v > v1) { v1 = v; b1 = i; }
        }
        sel0 = b0; sel1 = b1;
    }
    __syncthreads();   // act8 reads done before staging overwrites lds_raw

    const int z = blockIdx.z;
    const int idxz = z ? sel1 : sel0;
    const int m0 = blockIdx.x * 64;
    const int n0 = blockIdx.y * 128;
    const int wm = (wave >> 1) * 32;
    const int wn = (wave & 1) * 64;
    const int rl = lane & 15;
    const int quad = lane >> 4;

    const unsigned short* Atile = xbf + (size_t)m0 * 4096 + idxz * 512;
    const unsigned short* Btile = wct + (size_t)idxz * 262144 + (size_t)n0 * 512;

    f32x4_t acc[4][2] = {};   // [ni][mi] — operand-swapped mfma

    // stage K-step 0 into buffer 0
    #pragma unroll
    for (int s = wave; s < 8; s += 4)
        stage_glds(Atile, 4096, s * 8, (unsigned short*)lds_raw, lane);
    #pragma unroll
    for (int s = wave; s < 16; s += 4)
        stage_glds(Btile, 512, s * 8, (unsigned short*)(lds_raw + 16384), lane);
    __syncthreads();

    for (int t = 0; t < 8; ++t) {
        const int cb = t & 1;
        unsigned short* Ascur = (unsigned short*)(lds_raw + cb * 8192);
        unsigned short* Bscur = (unsigned short*)(lds_raw + 16384 + cb * 16384);
        if (t < 7) {   // prefetch next K-step into the other buffer
            unsigned short* Asnxt = (unsigned short*)(lds_raw + (cb ^ 1) * 8192);
            unsigned short* Bsnxt = (unsigned short*)(lds_raw + 16384 + (cb ^ 1) * 16384);
            const int k1 = (t + 1) * 64;
            #pragma unroll
            for (int s = wave; s < 8; s += 4)  stage_glds(Atile + k1, 4096, s * 8, Asnxt, lane);
            #pragma unroll
            for (int s = wave; s < 16; s += 4) stage_glds(Btile + k1, 512,  s * 8, Bsnxt, lane);
        }
        #pragma unroll
        for (int kq = 0; kq < 2; ++kq) {
            const int kb = kq * 32 + quad * 8;
            bf16x8_t af[2], bfr[4];
            #pragma unroll
            for (int i = 0; i < 2; ++i) af[i]  = ldsfrag(Ascur, wm + i * 16 + rl, kb);
            #pragma unroll
            for (int i = 0; i < 4; ++i) bfr[i] = ldsfrag(Bscur, wn + i * 16 + rl, kb);
            #pragma unroll
            for (int ni = 0; ni < 4; ++ni)
                #pragma unroll
                for (int mi = 0; mi < 2; ++mi)
                    acc[ni][mi] = __builtin_amdgcn_mfma_f32_16x16x32_bf16(bfr[ni], af[mi], acc[ni][mi], 0, 0, 0);
        }
        __syncthreads();   // drains the prefetch (vmcnt 0) + read-fence
    }

    // swapped layout: lane holds 4 consecutive N-cols -> ushort4 stores
    const float* bias = bc + (size_t)idxz * 512;
    #pragma unroll
    for (int ni = 0; ni < 4; ++ni) {
        const int colb = n0 + wn + ni * 16 + quad * 4;
        f32x4_t bv4 = *(const f32x4_t*)(bias + colb);
        #pragma unroll
        for (int mi = 0; mi < 2; ++mi) {
            int row = m0 + wm + mi * 16 + rl;
            f32x4_t o = acc[ni][mi] + bv4;
            u16x4 hv;
            #pragma unroll
            for (int j = 0; j < 4; ++j) hv[j] = f2bf(o[j]);
            *(u16x4*)(h + (size_t)row * 1024 + z * 512 + colb) = hv;
        }
    }
}

// ---------------- K3: GEMM2 — 128x128, 2-phase dbuf, XCD swizzle -----------
__global__ __launch_bounds__(256, 2)
void gemm2_kernel(const unsigned short* __restrict__ h, const unsigned short* __restrict__ wft,
                  const float* __restrict__ bfin, float* __restrict__ out) {
    __shared__ __align__(16) unsigned short As[2][128 * 64];   // 32 KB
    __shared__ __align__(16) unsigned short Bs[2][128 * 64];   // 32 KB

    // bijective XCD swizzle (1024 blocks, 1024%8==0): consecutive in-XCD
    // blocks share the B panel -> per-XCD L2 reuse
    const int f = blockIdx.x;
    const int g = (f & 7) * 128 + (f >> 3);
    const int m0 = (g & 31) * 128;
    const int n0 = (g >> 5) * 128;

    const int tid = threadIdx.x;
    const int wave = tid >> 6;
    const int lane = tid & 63;
    const int wm = (wave >> 1) * 64;
    const int wn = (wave & 1) * 64;
    const int rl = lane & 15;
    const int quad = lane >> 4;

    const unsigned short* Atile = h + (size_t)m0 * 1024;
    const unsigned short* Btile = wft + (size_t)n0 * 1024;

    f32x4_t acc[4][4] = {};   // [ni][mi] — operand-swapped mfma

    // stage K-step 0 into buffer 0
    #pragma unroll
    for (int s = wave; s < 32; s += 4) {
        if (s < 16) stage_glds(Atile, 1024, s * 8, As[0], lane);
        else        stage_glds(Btile, 1024, (s - 16) * 8, Bs[0], lane);
    }
    __syncthreads();

    for (int t = 0; t < 16; ++t) {
        const int cb = t & 1;
        if (t < 15) {   // prefetch next K-step into the other buffer
            const int k1 = (t + 1) * 64;
            #pragma unroll
            for (int s = wave; s < 32; s += 4) {
                if (s < 16) stage_glds(Atile + k1, 1024, s * 8, As[cb ^ 1], lane);
                else        stage_glds(Btile + k1, 1024, (s - 16) * 8, Bs[cb ^ 1], lane);
            }
        }
        #pragma unroll
        for (int kq = 0; kq < 2; ++kq) {
            const int kb = kq * 32 + quad * 8;
            bf16x8_t af[4], bfr[4];
            #pragma unroll
            for (int i = 0; i < 4; ++i) {
                af[i]  = ldsfrag(As[cb], wm + i * 16 + rl, kb);
                bfr[i] = ldsfrag(Bs[cb], wn + i * 16 + rl, kb);
            }
            #pragma unroll
            for (int ni = 0; ni < 4; ++ni)
                #pragma unroll
                for (int mi = 0; mi < 4; ++mi)
                    acc[ni][mi] = __builtin_amdgcn_mfma_f32_16x16x32_bf16(bfr[ni], af[mi], acc[ni][mi], 0, 0, 0);
        }
        __syncthreads();   // drains the prefetch (vmcnt 0) + read-fence
    }

    // swapped layout: lane holds 4 consecutive N-cols -> float4 stores
    #pragma unroll
    for (int ni = 0; ni < 4; ++ni) {
        const int colb = n0 + wn + ni * 16 + quad * 4;
        f32x4_t bv4 = *(const f32x4_t*)(bfin + colb);
        #pragma unroll
        for (int mi = 0; mi < 4; ++mi) {
            int row = m0 + wm + mi * 16 + rl;
            f32x4_t o = acc[ni][mi] + bv4;
            *(f32x4_t*)(out + (size_t)row * 4096 + colb) = o;
        }
    }
}

// ---------------------------------------------------------------------------
extern "C" void kernel_launch(void* const* d_in, const int* in_sizes, int n_in,
                              void* d_out, int out_size, void* d_ws, size_t ws_size,
                              hipStream_t stream) {
    const float* x    = (const float*)d_in[0];   // (4096, 4096)
    const float* Wc   = (const float*)d_in[1];   // (8, 512, 512)
    const float* bc   = (const float*)d_in[2];   // (8, 512)
    const float* Wf   = (const float*)d_in[3];   // (1024, 4096)
    const float* bfin = (const float*)d_in[4];   // (4096,)
    float* out = (float*)d_out;                  // (4096, 4096) fp32

    float* part = (float*)d_ws;                                    // 512 f32
    unsigned short* h   = (unsigned short*)((char*)d_ws + 4096);   // 4096x1024 bf16 (8 MB)
    unsigned short* wct = h   + (size_t)4096 * 1024;               // 8x512x512 bf16 (4 MB)
    unsigned short* wft = wct + (size_t)8 * 512 * 512;             // 4096x1024 bf16 (8 MB)
    unsigned short* xbf = wft + (size_t)4096 * 1024;               // 4096x4096 bf16 (32 MB)

    fused_prep_kernel<<<6656, 256, 0, stream>>>(x, Wc, Wf, part, wct, wft, xbf);
    gemm1_kernel<<<dim3(64, 4, 2), 256, 0, stream>>>(xbf, wct, bc, part, h);
    gemm2_kernel<<<1024, 256, 0, stream>>>(h, wft, bfin, out);
}

// Round 8
// 191.364 us; speedup vs baseline: 1.0800x; 1.0800x over previous
//
#include <hip/hip_runtime.h>

// ---------------------------------------------------------------------------
// R12: consolidation of verified pieces only.
//  - gemm2: R7 verbatim (best measured 42.4us; 818 TF ~= its structural
//    ceiling). XCD swizzle REVERTED (R11: it doubled L2-fill, 39->70MB).
//    Dbuf REVERTED (R11: MfmaUtil 30->22 at 2 blocks/CU).
//  - prep: R11 verbatim (emits bf16 xbf alongside activity; passed).
//  - gemm1: single-buffer (24KB, 4 blocks/CU) with BOTH operands staged via
//    global_load_lds from bf16 (A from xbf) — kills the 32MB fp32 x read and
//    the cvt+ds_write VALU path. Staging+epilogue pieces verified in R11.
// ---------------------------------------------------------------------------

typedef __bf16 bf16x8_t __attribute__((ext_vector_type(8)));
typedef float  f32x4_t  __attribute__((ext_vector_type(4)));
typedef unsigned short u16x4 __attribute__((ext_vector_type(4)));

__device__ inline unsigned short f2bf(float f) {
    __bf16 b = (__bf16)f;
    return __builtin_bit_cast(unsigned short, b);
}

// async stage of 8 rows (wave-uniform row0) from bf16 global, 16 B/lane,
// XOR-swizzled granules: LDS slot gs holds global granule gs ^ (row & 7)
__device__ inline void stage_glds(const unsigned short* gtile, int stride, int row0,
                                  unsigned short* lds, int lane) {
    const int r8 = lane >> 3;
    const int gg = (lane & 7) ^ r8;
    const unsigned short* gp = gtile + (size_t)(row0 + r8) * stride + gg * 8;
    unsigned short* lp = lds + row0 * 64;
    __builtin_amdgcn_global_load_lds((const __attribute__((address_space(1))) void*)gp,
                                     (__attribute__((address_space(3))) void*)lp,
                                     16, 0, 0);
}

__device__ inline bf16x8_t ldsfrag(const unsigned short* Ls, int row, int kb) {
    return *(const bf16x8_t*)(Ls + row * 64 + (((kb >> 3) ^ (row & 7)) * 8));
}

// ---------------- K1: activity + xbf emit + transposes ---------------------
__global__ void fused_prep_kernel(const float* __restrict__ x, const float* __restrict__ Wc,
                                  const float* __restrict__ Wf, float* __restrict__ part,
                                  unsigned short* __restrict__ wct, unsigned short* __restrict__ wft,
                                  unsigned short* __restrict__ xbf) {
    const int b = blockIdx.x;
    const int tid = threadIdx.x;

    if (b < 512) {
        const int chunk = b & 7;
        const int rg = b >> 3;
        const int colf4 = tid & 127;
        const int rsub = tid >> 7;
        const float4* base = (const float4*)x + (size_t)chunk * 128 + colf4;
        unsigned short* xdst = xbf + (size_t)chunk * 512 + colf4 * 4;
        float s = 0.f;
        #pragma unroll 4
        for (int i = 0; i < 32; ++i) {
            int row = rg * 64 + i * 2 + rsub;
            float4 v = base[(size_t)row * 1024];
            s += fabsf(v.x) + fabsf(v.y) + fabsf(v.z) + fabsf(v.w);
            u16x4 hv;
            hv[0] = f2bf(v.x); hv[1] = f2bf(v.y); hv[2] = f2bf(v.z); hv[3] = f2bf(v.w);
            *(u16x4*)(xdst + (size_t)row * 4096) = hv;
        }
        #pragma unroll
        for (int off = 32; off > 0; off >>= 1) s += __shfl_down(s, off, 64);
        __shared__ float wsum[4];
        if ((tid & 63) == 0) wsum[tid >> 6] = s;
        __syncthreads();
        if (tid == 0) part[chunk * 64 + rg] = wsum[0] + wsum[1] + wsum[2] + wsum[3];
        return;
    }

    __shared__ float tile[32][33];
    const int tx = tid & 31, ty = tid >> 5;
    const float* src; unsigned short* dst; int R, C, cb, rb;
    int jj = b - 512;
    if (jj < 4096) {                       // Wf^T: (1024,4096) -> (4096,1024)
        src = Wf; dst = wft; R = 1024; C = 4096;
        cb = (jj & 127) * 32; rb = (jj >> 7) * 32;
    } else {                               // Wc[c]^T for ALL c
        jj -= 4096;
        int c = jj >> 8, t = jj & 255;
        src = Wc + (size_t)c * 262144;
        dst = wct + (size_t)c * 262144;
        R = 512; C = 512;
        cb = (t & 15) * 32; rb = (t >> 4) * 32;
    }
    #pragma unroll
    for (int i = 0; i < 4; ++i)
        tile[ty + i * 8][tx] = src[(size_t)(rb + ty + i * 8) * C + cb + tx];
    __syncthreads();
    {
        const int tx8  = tid & 7;
        const int ty32 = tid >> 3;
        u16x4 hv;
        #pragma unroll
        for (int j = 0; j < 4; ++j) hv[j] = f2bf(tile[tx8 * 4 + j][ty32]);
        *(u16x4*)(dst + (size_t)(cb + ty32) * R + rb + tx8 * 4) = hv;
    }
}

// ---------------- K2: GEMM1 — glds A(xbf)+B, single buffer, 4 blk/CU -------
__global__ __launch_bounds__(256, 4)
void gemm1_kernel(const unsigned short* __restrict__ xbf, const unsigned short* __restrict__ wct,
                  const float* __restrict__ bc, const float* __restrict__ part,
                  unsigned short* __restrict__ h) {
    __shared__ __align__(16) unsigned char lds_raw[24576];
    unsigned short* As = (unsigned short*)lds_raw;            // 8 KB (64x64)
    unsigned short* Bs = (unsigned short*)(lds_raw + 8192);   // 16 KB (128x64)

    const int tid = threadIdx.x;
    const int wave = tid >> 6;
    const int lane = tid & 63;

    // prologue: reduce part[512] -> act[8] -> top-2 (redundant per block)
    {
        float* sred = (float*)lds_raw;
        sred[tid] = part[tid];
        sred[tid + 256] = part[tid + 256];
        __syncthreads();
        float* act8 = (float*)(lds_raw + 2048);
        if (tid < 8) {
            float a = 0.f;
            #pragma unroll
            for (int k = 0; k < 64; ++k) a += sred[tid * 64 + k];
            act8[tid] = a;
        }
        __syncthreads();
    }
    int sel0, sel1;
    {
        const float* act8 = (const float*)(lds_raw + 2048);
        float v0 = -1e30f, v1 = -1e30f; int b0 = 0, b1 = 0;
        #pragma unroll
        for (int i = 0; i < 8; ++i) {
            float v = act8[i];
            if (v > v0) { v1 = v0; b1 = b0; v0 = v; b0 = i; }
            else if (v > v1) { v1 = v; b1 = i; }
        }
        sel0 = b0; sel1 = b1;
    }
    __syncthreads();   // act8 reads done before staging overwrites lds_raw

    const int z = blockIdx.z;
    const int idxz = z ? sel1 : sel0;
    const int m0 = blockIdx.x * 64;
    const int n0 = blockIdx.y * 128;
    const int wm = (wave >> 1) * 32;
    const int wn = (wave & 1) * 64;
    const int rl = lane & 15;
    const int quad = lane >> 4;

    const unsigned short* Atile = xbf + (size_t)m0 * 4096 + idxz * 512;
    const unsigned short* Btile = wct + (size_t)idxz * 262144 + (size_t)n0 * 512;

    f32x4_t acc[4][2] = {};   // [ni][mi] — operand-swapped mfma

    for (int k0 = 0; k0 < 512; k0 += 64) {
        #pragma unroll
        for (int s = wave; s < 8; s += 4)
            stage_glds(Atile + k0, 4096, s * 8, As, lane);
        #pragma unroll
        for (int s = wave; s < 16; s += 4)
            stage_glds(Btile + k0, 512, s * 8, Bs, lane);
        __syncthreads();
        #pragma unroll
        for (int kq = 0; kq < 2; ++kq) {
            const int kb = kq * 32 + quad * 8;
            bf16x8_t af[2], bfr[4];
            #pragma unroll
            for (int i = 0; i < 2; ++i) af[i]  = ldsfrag(As, wm + i * 16 + rl, kb);
            #pragma unroll
            for (int i = 0; i < 4; ++i) bfr[i] = ldsfrag(Bs, wn + i * 16 + rl, kb);
            #pragma unroll
            for (int ni = 0; ni < 4; ++ni)
                #pragma unroll
                for (int mi = 0; mi < 2; ++mi)
                    acc[ni][mi] = __builtin_amdgcn_mfma_f32_16x16x32_bf16(bfr[ni], af[mi], acc[ni][mi], 0, 0, 0);
        }
        __syncthreads();
    }

    // swapped layout: lane holds 4 consecutive N-cols -> ushort4 stores
    const float* bias = bc + (size_t)idxz * 512;
    #pragma unroll
    for (int ni = 0; ni < 4; ++ni) {
        const int colb = n0 + wn + ni * 16 + quad * 4;
        f32x4_t bv4 = *(const f32x4_t*)(bias + colb);
        #pragma unroll
        for (int mi = 0; mi < 2; ++mi) {
            int row = m0 + wm + mi * 16 + rl;
            f32x4_t o = acc[ni][mi] + bv4;
            u16x4 hv;
            #pragma unroll
            for (int j = 0; j < 4; ++j) hv[j] = f2bf(o[j]);
            *(u16x4*)(h + (size_t)row * 1024 + z * 512 + colb) = hv;
        }
    }
}

// ---------------- K3: GEMM2 — R7 verbatim (128x128, 4 blk/CU) --------------
__global__ __launch_bounds__(256, 4)
void gemm2_kernel(const unsigned short* __restrict__ h, const unsigned short* __restrict__ wft,
                  const float* __restrict__ bfin, float* __restrict__ out) {
    __shared__ __align__(16) unsigned short As[128 * 64];   // 16 KB
    __shared__ __align__(16) unsigned short Bs[128 * 64];   // 16 KB
    const int m0 = blockIdx.x * 128;
    const int n0 = blockIdx.y * 128;
    const int tid = threadIdx.x;
    const int wave = tid >> 6;
    const int lane = tid & 63;
    const int wm = (wave >> 1) * 64;
    const int wn = (wave & 1) * 64;
    const int rl = lane & 15;
    const int quad = lane >> 4;

    const unsigned short* Atile = h + (size_t)m0 * 1024;
    const unsigned short* Btile = wft + (size_t)n0 * 1024;

    f32x4_t acc[4][4] = {};

    for (int k0 = 0; k0 < 1024; k0 += 64) {
        #pragma unroll
        for (int s = wave; s < 32; s += 4) {
            if (s < 16) stage_glds(Atile + k0, 1024, s * 8, As, lane);
            else        stage_glds(Btile + k0, 1024, (s - 16) * 8, Bs, lane);
        }
        __syncthreads();
        #pragma unroll
        for (int kq = 0; kq < 2; ++kq) {
            const int kb = kq * 32 + quad * 8;
            bf16x8_t af[4], bfr[4];
            #pragma unroll
            for (int i = 0; i < 4; ++i) {
                af[i]  = ldsfrag(As, wm + i * 16 + rl, kb);
                bfr[i] = ldsfrag(Bs, wn + i * 16 + rl, kb);
            }
            #pragma unroll
            for (int mi = 0; mi < 4; ++mi)
                #pragma unroll
                for (int ni = 0; ni < 4; ++ni)
                    acc[mi][ni] = __builtin_amdgcn_mfma_f32_16x16x32_bf16(af[mi], bfr[ni], acc[mi][ni], 0, 0, 0);
        }
        __syncthreads();
    }

    // epilogue: j-outer so consecutive stores walk within/near rows
    const int row_l = quad * 4;
    float bv[4];
    #pragma unroll
    for (int ni = 0; ni < 4; ++ni) bv[ni] = bfin[n0 + wn + ni * 16 + rl];
    #pragma unroll
    for (int j = 0; j < 4; ++j) {
        #pragma unroll
        for (int mi = 0; mi < 4; ++mi) {
            int row = m0 + wm + mi * 16 + row_l + j;
            float* orow = out + (size_t)row * 4096 + n0 + wn + rl;
            #pragma unroll
            for (int ni = 0; ni < 4; ++ni)
                orow[ni * 16] = acc[mi][ni][j] + bv[ni];
        }
    }
}

// ---------------------------------------------------------------------------
extern "C" void kernel_launch(void* const* d_in, const int* in_sizes, int n_in,
                              void* d_out, int out_size, void* d_ws, size_t ws_size,
                              hipStream_t stream) {
    const float* x    = (const float*)d_in[0];   // (4096, 4096)
    const float* Wc   = (const float*)d_in[1];   // (8, 512, 512)
    const float* bc   = (const float*)d_in[2];   // (8, 512)
    const float* Wf   = (const float*)d_in[3];   // (1024, 4096)
    const float* bfin = (const float*)d_in[4];   // (4096,)
    float* out = (float*)d_out;                  // (4096, 4096) fp32

    float* part = (float*)d_ws;                                    // 512 f32
    unsigned short* h   = (unsigned short*)((char*)d_ws + 4096);   // 4096x1024 bf16 (8 MB)
    unsigned short* wct = h   + (size_t)4096 * 1024;               // 8x512x512 bf16 (4 MB)
    unsigned short* wft = wct + (size_t)8 * 512 * 512;             // 4096x1024 bf16 (8 MB)
    unsigned short* xbf = wft + (size_t)4096 * 1024;               // 4096x4096 bf16 (32 MB)

    fused_prep_kernel<<<6656, 256, 0, stream>>>(x, Wc, Wf, part, wct, wft, xbf);
    gemm1_kernel<<<dim3(64, 4, 2), 256, 0, stream>>>(xbf, wct, bc, part, h);
    gemm2_kernel<<<dim3(32, 32, 1), 256, 0, stream>>>(h, wft, bfin, out);
}

// Round 9
// 188.286 us; speedup vs baseline: 1.0976x; 1.0163x over previous
//
#include <hip/hip_runtime.h>

// ---------------------------------------------------------------------------
// R13: consolidation + nt-store epilogue.
//  - prep: R9 verbatim (NO xbf — R12 proved xbf is 32MB written to save 8MB
//    read, net loss; gemm1's cvt path was never the bottleneck).
//  - gemm1: R9 verbatim (fp32 x gather; measured-equivalent to glds variant).
//  - gemm2: R7 structure (measured best, 42.4-43.5us) + NEW:
//    __builtin_nontemporal_store for out. FETCH=39MB vs 16MB true read set;
//    the ~23MB phantom = write-allocate fills for the 64MB streaming out.
//    nt-stores bypass allocation -> predict FETCH ~17-20MB, dur ~37-40us.
//  - workspace back to 20MB (total tracked ws size in R7->R12 deltas).
// ---------------------------------------------------------------------------

typedef __bf16 bf16x8_t __attribute__((ext_vector_type(8)));
typedef float  f32x4_t  __attribute__((ext_vector_type(4)));
typedef unsigned short u16x4 __attribute__((ext_vector_type(4)));

__device__ inline unsigned short f2bf(float f) {
    __bf16 b = (__bf16)f;
    return __builtin_bit_cast(unsigned short, b);
}

// async stage of 8 rows (wave-uniform row0) from bf16 global, 16 B/lane,
// XOR-swizzled granules: LDS slot gs holds global granule gs ^ (row & 7)
__device__ inline void stage_glds(const unsigned short* gtile, int stride, int row0,
                                  unsigned short* lds, int lane) {
    const int r8 = lane >> 3;
    const int gg = (lane & 7) ^ r8;
    const unsigned short* gp = gtile + (size_t)(row0 + r8) * stride + gg * 8;
    unsigned short* lp = lds + row0 * 64;
    __builtin_amdgcn_global_load_lds((const __attribute__((address_space(1))) void*)gp,
                                     (__attribute__((address_space(3))) void*)lp,
                                     16, 0, 0);
}

__device__ inline bf16x8_t ldsfrag(const unsigned short* Ls, int row, int kb) {
    return *(const bf16x8_t*)(Ls + row * 64 + (((kb >> 3) ^ (row & 7)) * 8));
}

// ---------------- K1: fused activity-partials + all transposes -------------
__global__ void fused_prep_kernel(const float* __restrict__ x, const float* __restrict__ Wc,
                                  const float* __restrict__ Wf, float* __restrict__ part,
                                  unsigned short* __restrict__ wct, unsigned short* __restrict__ wft) {
    const int b = blockIdx.x;
    const int tid = threadIdx.x;

    if (b < 512) {
        const int chunk = b & 7;
        const int rg = b >> 3;
        const int colf4 = tid & 127;
        const int rsub = tid >> 7;
        const float4* base = (const float4*)x + (size_t)chunk * 128 + colf4;
        float s = 0.f;
        #pragma unroll 4
        for (int i = 0; i < 32; ++i) {
            int row = rg * 64 + i * 2 + rsub;
            float4 v = base[(size_t)row * 1024];
            s += fabsf(v.x) + fabsf(v.y) + fabsf(v.z) + fabsf(v.w);
        }
        #pragma unroll
        for (int off = 32; off > 0; off >>= 1) s += __shfl_down(s, off, 64);
        __shared__ float wsum[4];
        if ((tid & 63) == 0) wsum[tid >> 6] = s;
        __syncthreads();
        if (tid == 0) part[chunk * 64 + rg] = wsum[0] + wsum[1] + wsum[2] + wsum[3];
        return;
    }

    __shared__ float tile[32][33];
    const int tx = tid & 31, ty = tid >> 5;
    const float* src; unsigned short* dst; int R, C, cb, rb;
    int jj = b - 512;
    if (jj < 4096) {                       // Wf^T: (1024,4096) -> (4096,1024)
        src = Wf; dst = wft; R = 1024; C = 4096;
        cb = (jj & 127) * 32; rb = (jj >> 7) * 32;
    } else {                               // Wc[c]^T for ALL c
        jj -= 4096;
        int c = jj >> 8, t = jj & 255;
        src = Wc + (size_t)c * 262144;
        dst = wct + (size_t)c * 262144;
        R = 512; C = 512;
        cb = (t & 15) * 32; rb = (t >> 4) * 32;
    }
    #pragma unroll
    for (int i = 0; i < 4; ++i)
        tile[ty + i * 8][tx] = src[(size_t)(rb + ty + i * 8) * C + cb + tx];
    __syncthreads();
    // vectorized transpose store: thread (tx8, ty32) writes 4 consecutive
    // dst cols as ushort4 (8 B/lane). LDS read bank pattern is 2-way (free).
    {
        const int tx8  = tid & 7;
        const int ty32 = tid >> 3;
        u16x4 hv;
        #pragma unroll
        for (int j = 0; j < 4; ++j) hv[j] = f2bf(tile[tx8 * 4 + j][ty32]);
        *(u16x4*)(dst + (size_t)(cb + ty32) * R + rb + tx8 * 4) = hv;
    }
}

// ---------------- K2: GEMM1 — topk prologue + fused fp32 gather ------------
__global__ __launch_bounds__(256, 4)
void gemm1_kernel(const float* __restrict__ x, const unsigned short* __restrict__ wct,
                  const float* __restrict__ bc, const float* __restrict__ part,
                  unsigned short* __restrict__ h) {
    __shared__ __align__(16) unsigned char lds_raw[24576];
    unsigned short* As = (unsigned short*)lds_raw;            // 8 KB (64x64)
    unsigned short* Bs = (unsigned short*)(lds_raw + 8192);   // 16 KB (128x64)

    const int tid = threadIdx.x;
    const int wave = tid >> 6;
    const int lane = tid & 63;

    // prologue: reduce part[512] -> act[8] -> top-2 (redundant per block)
    {
        float* sred = (float*)lds_raw;
        sred[tid] = part[tid];
        sred[tid + 256] = part[tid + 256];
        __syncthreads();
        float* act8 = (float*)(lds_raw + 2048);
        if (tid < 8) {
            float a = 0.f;
            #pragma unroll
            for (int k = 0; k < 64; ++k) a += sred[tid * 64 + k];
            act8[tid] = a;
        }
        __syncthreads();
    }
    int sel0, sel1;
    {
        const float* act8 = (const float*)(lds_raw + 2048);
        float v0 = -1e30f, v1 = -1e30f; int b0 = 0, b1 = 0;
        #pragma unroll
        for (int i = 0; i < 8; ++i) {
            float v = act8[i];
            if (v > v0) { v1 = v0; b1 = b0; v0 = v; b0 = i; }
            else if (v > v1) { v1 = v; b1 = i; }
        }
        sel0 = b0; sel1 = b1;
    }
    __syncthreads();

    const int z = blockIdx.z;
    const int idxz = z ? sel1 : sel0;
    const int m0 = blockIdx.x * 64;
    const int n0 = blockIdx.y * 128;
    const int wm = (wave >> 1) * 32;
    const int wn = (wave & 1) * 64;
    const int rl = lane & 15;
    const int quad = lane >> 4;

    const float* xtile = x + (size_t)m0 * 4096 + idxz * 512;
    const unsigned short* Btile = wct + (size_t)idxz * 262144 + (size_t)n0 * 512;

    f32x4_t acc[4][2] = {};   // [ni][mi] — operand-swapped mfma
    const int ar = tid >> 2;
    const int aq = tid & 3;

    for (int k0 = 0; k0 < 512; k0 += 64) {
        #pragma unroll
        for (int s = wave; s < 16; s += 4)
            stage_glds(Btile + k0, 512, s * 8, Bs, lane);
        const float* gr = xtile + (size_t)ar * 4096 + k0;
        #pragma unroll
        for (int j = 0; j < 2; ++j) {
            int gg = aq * 2 + j;
            float4 a = *(const float4*)(gr + gg * 8);
            float4 c = *(const float4*)(gr + gg * 8 + 4);
            bf16x8_t v;
            v[0] = (__bf16)a.x; v[1] = (__bf16)a.y; v[2] = (__bf16)a.z; v[3] = (__bf16)a.w;
            v[4] = (__bf16)c.x; v[5] = (__bf16)c.y; v[6] = (__bf16)c.z; v[7] = (__bf16)c.w;
            *(bf16x8_t*)(As + ar * 64 + ((gg ^ (ar & 7)) * 8)) = v;
        }
        __syncthreads();
        #pragma unroll
        for (int kq = 0; kq < 2; ++kq) {
            const int kb = kq * 32 + quad * 8;
            bf16x8_t af[2], bfr[4];
            #pragma unroll
            for (int i = 0; i < 2; ++i) af[i]  = ldsfrag(As, wm + i * 16 + rl, kb);
            #pragma unroll
            for (int i = 0; i < 4; ++i) bfr[i] = ldsfrag(Bs, wn + i * 16 + rl, kb);
            #pragma unroll
            for (int ni = 0; ni < 4; ++ni)
                #pragma unroll
                for (int mi = 0; mi < 2; ++mi)
                    acc[ni][mi] = __builtin_amdgcn_mfma_f32_16x16x32_bf16(bfr[ni], af[mi], acc[ni][mi], 0, 0, 0);
        }
        __syncthreads();
    }

    // swapped layout: lane holds 4 consecutive N-cols -> ushort4 stores
    const float* bias = bc + (size_t)idxz * 512;
    #pragma unroll
    for (int ni = 0; ni < 4; ++ni) {
        const int colb = n0 + wn + ni * 16 + quad * 4;
        f32x4_t bv4 = *(const f32x4_t*)(bias + colb);
        #pragma unroll
        for (int mi = 0; mi < 2; ++mi) {
            int row = m0 + wm + mi * 16 + rl;
            f32x4_t o = acc[ni][mi] + bv4;
            u16x4 hv;
            #pragma unroll
            for (int j = 0; j < 4; ++j) hv[j] = f2bf(o[j]);
            *(u16x4*)(h + (size_t)row * 1024 + z * 512 + colb) = hv;
        }
    }
}

// ---------------- K3: GEMM2 — R7 structure + nontemporal out stores --------
__global__ __launch_bounds__(256, 4)
void gemm2_kernel(const unsigned short* __restrict__ h, const unsigned short* __restrict__ wft,
                  const float* __restrict__ bfin, float* __restrict__ out) {
    __shared__ __align__(16) unsigned short As[128 * 64];   // 16 KB
    __shared__ __align__(16) unsigned short Bs[128 * 64];   // 16 KB
    const int m0 = blockIdx.x * 128;
    const int n0 = blockIdx.y * 128;
    const int tid = threadIdx.x;
    const int wave = tid >> 6;
    const int lane = tid & 63;
    const int wm = (wave >> 1) * 64;
    const int wn = (wave & 1) * 64;
    const int rl = lane & 15;
    const int quad = lane >> 4;

    const unsigned short* Atile = h + (size_t)m0 * 1024;
    const unsigned short* Btile = wft + (size_t)n0 * 1024;

    f32x4_t acc[4][4] = {};

    for (int k0 = 0; k0 < 1024; k0 += 64) {
        #pragma unroll
        for (int s = wave; s < 32; s += 4) {
            if (s < 16) stage_glds(Atile + k0, 1024, s * 8, As, lane);
            else        stage_glds(Btile + k0, 1024, (s - 16) * 8, Bs, lane);
        }
        __syncthreads();
        #pragma unroll
        for (int kq = 0; kq < 2; ++kq) {
            const int kb = kq * 32 + quad * 8;
            bf16x8_t af[4], bfr[4];
            #pragma unroll
            for (int i = 0; i < 4; ++i) {
                af[i]  = ldsfrag(As, wm + i * 16 + rl, kb);
                bfr[i] = ldsfrag(Bs, wn + i * 16 + rl, kb);
            }
            #pragma unroll
            for (int mi = 0; mi < 4; ++mi)
                #pragma unroll
                for (int ni = 0; ni < 4; ++ni)
                    acc[mi][ni] = __builtin_amdgcn_mfma_f32_16x16x32_bf16(af[mi], bfr[ni], acc[mi][ni], 0, 0, 0);
        }
        __syncthreads();
    }

    // epilogue: j-outer (measured-best), stores nontemporal — out is
    // write-once/never-read; avoid write-allocate fills (the ~23MB phantom
    // FETCH) and L3 pollution.
    const int row_l = quad * 4;
    float bv[4];
    #pragma unroll
    for (int ni = 0; ni < 4; ++ni) bv[ni] = bfin[n0 + wn + ni * 16 + rl];
    #pragma unroll
    for (int j = 0; j < 4; ++j) {
        #pragma unroll
        for (int mi = 0; mi < 4; ++mi) {
            int row = m0 + wm + mi * 16 + row_l + j;
            float* orow = out + (size_t)row * 4096 + n0 + wn + rl;
            #pragma unroll
            for (int ni = 0; ni < 4; ++ni)
                __builtin_nontemporal_store(acc[mi][ni][j] + bv[ni], &orow[ni * 16]);
        }
    }
}

// ---------------------------------------------------------------------------
extern "C" void kernel_launch(void* const* d_in, const int* in_sizes, int n_in,
                              void* d_out, int out_size, void* d_ws, size_t ws_size,
                              hipStream_t stream) {
    const float* x    = (const float*)d_in[0];   // (4096, 4096)
    const float* Wc   = (const float*)d_in[1];   // (8, 512, 512)
    const float* bc   = (const float*)d_in[2];   // (8, 512)
    const float* Wf   = (const float*)d_in[3];   // (1024, 4096)
    const float* bfin = (const float*)d_in[4];   // (4096,)
    float* out = (float*)d_out;                  // (4096, 4096) fp32

    float* part = (float*)d_ws;                                    // 512 f32
    unsigned short* h   = (unsigned short*)((char*)d_ws + 4096);   // 4096x1024 bf16
    unsigned short* wct = h   + (size_t)4096 * 1024;               // 8x512x512 bf16
    unsigned short* wft = wct + (size_t)8 * 512 * 512;             // 4096x1024 bf16

    fused_prep_kernel<<<6656, 256, 0, stream>>>(x, Wc, Wf, part, wct, wft);
    gemm1_kernel<<<dim3(64, 4, 2), 256, 0, stream>>>(x, wct, bc, part, h);
    gemm2_kernel<<<dim3(32, 32, 1), 256, 0, stream>>>(h, wft, bfin, out);
}

// Round 10
// 185.332 us; speedup vs baseline: 1.1151x; 1.0159x over previous
//
#include <hip/hip_runtime.h>

// ---------------------------------------------------------------------------
// R14: gemm2 rebuilt as 256x256 / BK=32 / 4-slot ring / counted vmcnt(8).
//  - 512 thr, 8 waves (2Mx4N), per-wave 128x64 out, acc[8][4]
//  - ring: slot t&3 holds K-tile t; stage tile t+3 during tile t's compute
//  - ONE s_waitcnt vmcnt(8) + ONE raw s_barrier per K-tile (non-draining;
//    gate waits exactly tile t's 4 loads/thread, tiles t+1,t+2 stay in flight)
//  - setprio(1) around MFMA clusters; no sched_barrier pinning (R8's mistake)
//  - stage32/ldsfrag32 swizzle pair carried from R8 (harness-verified correct)
//  - restage tile 31 into dead slots at t>=29 keeps vmcnt count uniform
// prep/gemm1: R13 verbatim (passed 3x). gemm2 epilogue: plain scalar j-outer
// (R7-verified mapping; nt-store was neutral, reverted).
// ---------------------------------------------------------------------------

typedef __bf16 bf16x8_t __attribute__((ext_vector_type(8)));
typedef float  f32x4_t  __attribute__((ext_vector_type(4)));
typedef unsigned short u16x4 __attribute__((ext_vector_type(4)));

__device__ inline unsigned short f2bf(float f) {
    __bf16 b = (__bf16)f;
    return __builtin_bit_cast(unsigned short, b);
}

// ---- BK=64 helpers (gemm1) ------------------------------------------------
__device__ inline void stage_glds(const unsigned short* gtile, int stride, int row0,
                                  unsigned short* lds, int lane) {
    const int r8 = lane >> 3;
    const int gg = (lane & 7) ^ r8;
    const unsigned short* gp = gtile + (size_t)(row0 + r8) * stride + gg * 8;
    unsigned short* lp = lds + row0 * 64;
    __builtin_amdgcn_global_load_lds((const __attribute__((address_space(1))) void*)gp,
                                     (__attribute__((address_space(3))) void*)lp,
                                     16, 0, 0);
}

__device__ inline bf16x8_t ldsfrag(const unsigned short* Ls, int row, int kb) {
    return *(const bf16x8_t*)(Ls + row * 64 + (((kb >> 3) ^ (row & 7)) * 8));
}

// ---- BK=32 helpers (gemm2 ring; R8-verified pair) -------------------------
// rows are 32 shorts (64 B) = 4 granules of 8 shorts; one wave call stages
// 16 rows (1 KiB). LDS granule slot s of row r holds global granule
// s ^ ((r>>1)&3); global stride fixed at 1024 shorts (h and wft).
__device__ inline void stage32(const unsigned short* gtile, int row0,
                               unsigned short* lds, int lane) {
    const int r  = lane >> 2;                       // 0..15
    const int gg = (lane & 3) ^ ((r >> 1) & 3);
    const unsigned short* gp = gtile + (size_t)(row0 + r) * 1024 + gg * 8;
    unsigned short* lp = lds + row0 * 32;           // wave-uniform base
    __builtin_amdgcn_global_load_lds((const __attribute__((address_space(1))) void*)gp,
                                     (__attribute__((address_space(3))) void*)lp,
                                     16, 0, 0);
}

__device__ inline bf16x8_t ldsfrag32(const unsigned short* Ls, int row, int kb) {
    return *(const bf16x8_t*)(Ls + row * 32 + ((((kb >> 3) ^ ((row >> 1) & 3))) * 8));
}

// ---------------- K1: fused activity-partials + all transposes -------------
__global__ void fused_prep_kernel(const float* __restrict__ x, const float* __restrict__ Wc,
                                  const float* __restrict__ Wf, float* __restrict__ part,
                                  unsigned short* __restrict__ wct, unsigned short* __restrict__ wft) {
    const int b = blockIdx.x;
    const int tid = threadIdx.x;

    if (b < 512) {
        const int chunk = b & 7;
        const int rg = b >> 3;
        const int colf4 = tid & 127;
        const int rsub = tid >> 7;
        const float4* base = (const float4*)x + (size_t)chunk * 128 + colf4;
        float s = 0.f;
        #pragma unroll 4
        for (int i = 0; i < 32; ++i) {
            int row = rg * 64 + i * 2 + rsub;
            float4 v = base[(size_t)row * 1024];
            s += fabsf(v.x) + fabsf(v.y) + fabsf(v.z) + fabsf(v.w);
        }
        #pragma unroll
        for (int off = 32; off > 0; off >>= 1) s += __shfl_down(s, off, 64);
        __shared__ float wsum[4];
        if ((tid & 63) == 0) wsum[tid >> 6] = s;
        __syncthreads();
        if (tid == 0) part[chunk * 64 + rg] = wsum[0] + wsum[1] + wsum[2] + wsum[3];
        return;
    }

    __shared__ float tile[32][33];
    const int tx = tid & 31, ty = tid >> 5;
    const float* src; unsigned short* dst; int R, C, cb, rb;
    int jj = b - 512;
    if (jj < 4096) {                       // Wf^T: (1024,4096) -> (4096,1024)
        src = Wf; dst = wft; R = 1024; C = 4096;
        cb = (jj & 127) * 32; rb = (jj >> 7) * 32;
    } else {                               // Wc[c]^T for ALL c
        jj -= 4096;
        int c = jj >> 8, t = jj & 255;
        src = Wc + (size_t)c * 262144;
        dst = wct + (size_t)c * 262144;
        R = 512; C = 512;
        cb = (t & 15) * 32; rb = (t >> 4) * 32;
    }
    #pragma unroll
    for (int i = 0; i < 4; ++i)
        tile[ty + i * 8][tx] = src[(size_t)(rb + ty + i * 8) * C + cb + tx];
    __syncthreads();
    {
        const int tx8  = tid & 7;
        const int ty32 = tid >> 3;
        u16x4 hv;
        #pragma unroll
        for (int j = 0; j < 4; ++j) hv[j] = f2bf(tile[tx8 * 4 + j][ty32]);
        *(u16x4*)(dst + (size_t)(cb + ty32) * R + rb + tx8 * 4) = hv;
    }
}

// ---------------- K2: GEMM1 — topk prologue + fused fp32 gather ------------
__global__ __launch_bounds__(256, 4)
void gemm1_kernel(const float* __restrict__ x, const unsigned short* __restrict__ wct,
                  const float* __restrict__ bc, const float* __restrict__ part,
                  unsigned short* __restrict__ h) {
    __shared__ __align__(16) unsigned char lds_raw[24576];
    unsigned short* As = (unsigned short*)lds_raw;            // 8 KB (64x64)
    unsigned short* Bs = (unsigned short*)(lds_raw + 8192);   // 16 KB (128x64)

    const int tid = threadIdx.x;
    const int wave = tid >> 6;
    const int lane = tid & 63;

    {
        float* sred = (float*)lds_raw;
        sred[tid] = part[tid];
        sred[tid + 256] = part[tid + 256];
        __syncthreads();
        float* act8 = (float*)(lds_raw + 2048);
        if (tid < 8) {
            float a = 0.f;
            #pragma unroll
            for (int k = 0; k < 64; ++k) a += sred[tid * 64 + k];
            act8[tid] = a;
        }
        __syncthreads();
    }
    int sel0, sel1;
    {
        const float* act8 = (const float*)(lds_raw + 2048);
        float v0 = -1e30f, v1 = -1e30f; int b0 = 0, b1 = 0;
        #pragma unroll
        for (int i = 0; i < 8; ++i) {
            float v = act8[i];
            if (v > v0) { v1 = v0; b1 = b0; v0 = v; b0 = i; }
            else if (v > v1) { v1 = v; b1 = i; }
        }
        sel0 = b0; sel1 = b1;
    }
    __syncthreads();

    const int z = blockIdx.z;
    const int idxz = z ? sel1 : sel0;
    const int m0 = blockIdx.x * 64;
    const int n0 = blockIdx.y * 128;
    const int wm = (wave >> 1) * 32;
    const int wn = (wave & 1) * 64;
    const int rl = lane & 15;
    const int quad = lane >> 4;

    const float* xtile = x + (size_t)m0 * 4096 + idxz * 512;
    const unsigned short* Btile = wct + (size_t)idxz * 262144 + (size_t)n0 * 512;

    f32x4_t acc[4][2] = {};   // [ni][mi] — operand-swapped mfma
    const int ar = tid >> 2;
    const int aq = tid & 3;

    for (int k0 = 0; k0 < 512; k0 += 64) {
        #pragma unroll
        for (int s = wave; s < 16; s += 4)
            stage_glds(Btile + k0, 512, s * 8, Bs, lane);
        const float* gr = xtile + (size_t)ar * 4096 + k0;
        #pragma unroll
        for (int j = 0; j < 2; ++j) {
            int gg = aq * 2 + j;
            float4 a = *(const float4*)(gr + gg * 8);
            float4 c = *(const float4*)(gr + gg * 8 + 4);
            bf16x8_t v;
            v[0] = (__bf16)a.x; v[1] = (__bf16)a.y; v[2] = (__bf16)a.z; v[3] = (__bf16)a.w;
            v[4] = (__bf16)c.x; v[5] = (__bf16)c.y; v[6] = (__bf16)c.z; v[7] = (__bf16)c.w;
            *(bf16x8_t*)(As + ar * 64 + ((gg ^ (ar & 7)) * 8)) = v;
        }
        __syncthreads();
        #pragma unroll
        for (int kq = 0; kq < 2; ++kq) {
            const int kb = kq * 32 + quad * 8;
            bf16x8_t af[2], bfr[4];
            #pragma unroll
            for (int i = 0; i < 2; ++i) af[i]  = ldsfrag(As, wm + i * 16 + rl, kb);
            #pragma unroll
            for (int i = 0; i < 4; ++i) bfr[i] = ldsfrag(Bs, wn + i * 16 + rl, kb);
            #pragma unroll
            for (int ni = 0; ni < 4; ++ni)
                #pragma unroll
                for (int mi = 0; mi < 2; ++mi)
                    acc[ni][mi] = __builtin_amdgcn_mfma_f32_16x16x32_bf16(bfr[ni], af[mi], acc[ni][mi], 0, 0, 0);
        }
        __syncthreads();
    }

    const float* bias = bc + (size_t)idxz * 512;
    #pragma unroll
    for (int ni = 0; ni < 4; ++ni) {
        const int colb = n0 + wn + ni * 16 + quad * 4;
        f32x4_t bv4 = *(const f32x4_t*)(bias + colb);
        #pragma unroll
        for (int mi = 0; mi < 2; ++mi) {
            int row = m0 + wm + mi * 16 + rl;
            f32x4_t o = acc[ni][mi] + bv4;
            u16x4 hv;
            #pragma unroll
            for (int j = 0; j < 4; ++j) hv[j] = f2bf(o[j]);
            *(u16x4*)(h + (size_t)row * 1024 + z * 512 + colb) = hv;
        }
    }
}

// ---------------- K3: GEMM2 — 256x256, BK=32, 4-slot ring, vmcnt(8) --------
__global__ __launch_bounds__(512, 2)
void gemm2_kernel(const unsigned short* __restrict__ h, const unsigned short* __restrict__ wft,
                  const float* __restrict__ bfin, float* __restrict__ out) {
    // A slots: 4 x 256x32 bf16 @ 0,8192,16384,24576 (shorts)
    // B slots: 4 x 256x32 bf16 @ 32768 + same    -> 128 KiB total
    __shared__ __align__(16) unsigned short lds[65536];

    const int tid  = threadIdx.x;
    const int wv   = tid >> 6;
    const int lane = tid & 63;
    const int m0 = blockIdx.x * 256;
    const int n0 = blockIdx.y * 256;
    const int wmo = (wv >> 2) * 128;      // 2 M-groups
    const int wno = (wv & 3) * 64;        // 4 N-groups
    const int rl   = lane & 15;
    const int quad = lane >> 4;
    const int kb   = quad * 8;            // k-slice within BK=32
    const int srow = wv * 32;             // staging rows owned by this wave

    const unsigned short* Atile = h   + (size_t)m0 * 1024;
    const unsigned short* Btile = wft + (size_t)n0 * 1024;

    f32x4_t acc[8][4] = {};

    // prologue: stage K-tiles 0..2 into slots 0..2 (12 loads/thread in flight)
    #pragma unroll
    for (int p = 0; p < 3; ++p) {
        unsigned short* Ap = lds + p * 8192;
        unsigned short* Bp = lds + 32768 + p * 8192;
        stage32(Atile + p * 32, srow,      Ap, lane);
        stage32(Atile + p * 32, srow + 16, Ap, lane);
        stage32(Btile + p * 32, srow,      Bp, lane);
        stage32(Btile + p * 32, srow + 16, Bp, lane);
    }

    #pragma unroll 4
    for (int t = 0; t < 32; ++t) {
        const unsigned short* Ac = lds + (t & 3) * 8192;
        const unsigned short* Bc = lds + 32768 + (t & 3) * 8192;
        const int tn = (t + 3 < 32) ? t + 3 : 31;   // restage keeps count uniform
        unsigned short* An = lds + ((t + 3) & 3) * 8192;
        unsigned short* Bn = lds + 32768 + ((t + 3) & 3) * 8192;

        // gate: wait exactly tile t's 4 loads (tiles t+1,t+2 = 8 stay in
        // flight); barrier makes slot completeness block-wide. Non-draining.
        asm volatile("s_waitcnt vmcnt(8)" ::: "memory");
        __builtin_amdgcn_s_barrier();
        __builtin_amdgcn_sched_barrier(0);

        // phase 0: B-frags + A-rows wmo..wmo+63; stage A of tile t+3
        bf16x8_t bf[4], af[4];
        #pragma unroll
        for (int i = 0; i < 4; ++i) bf[i] = ldsfrag32(Bc, wno + i * 16 + rl, kb);
        #pragma unroll
        for (int i = 0; i < 4; ++i) af[i] = ldsfrag32(Ac, wmo + i * 16 + rl, kb);
        stage32(Atile + tn * 32, srow,      An, lane);
        stage32(Atile + tn * 32, srow + 16, An, lane);
        __builtin_amdgcn_s_setprio(1);
        #pragma unroll
        for (int mi = 0; mi < 4; ++mi)
            #pragma unroll
            for (int ni = 0; ni < 4; ++ni)
                acc[mi][ni] = __builtin_amdgcn_mfma_f32_16x16x32_bf16(af[mi], bf[ni], acc[mi][ni], 0, 0, 0);
        __builtin_amdgcn_s_setprio(0);

        // phase 1: A-rows wmo+64..wmo+127 (bf reused); stage B of tile t+3
        bf16x8_t ag[4];
        #pragma unroll
        for (int i = 0; i < 4; ++i) ag[i] = ldsfrag32(Ac, wmo + 64 + i * 16 + rl, kb);
        stage32(Btile + tn * 32, srow,      Bn, lane);
        stage32(Btile + tn * 32, srow + 16, Bn, lane);
        __builtin_amdgcn_s_setprio(1);
        #pragma unroll
        for (int mi = 0; mi < 4; ++mi)
            #pragma unroll
            for (int ni = 0; ni < 4; ++ni)
                acc[4 + mi][ni] = __builtin_amdgcn_mfma_f32_16x16x32_bf16(ag[mi], bf[ni], acc[4 + mi][ni], 0, 0, 0);
        __builtin_amdgcn_s_setprio(0);
    }
    // drain tail restages before kernel end (LDS lifetime)
    asm volatile("s_waitcnt vmcnt(0)" ::: "memory");

    // epilogue: j-outer scalar stores (R7-verified mapping)
    const int row_l = quad * 4;
    float bv[4];
    #pragma unroll
    for (int ni = 0; ni < 4; ++ni) bv[ni] = bfin[n0 + wno + ni * 16 + rl];
    #pragma unroll
    for (int j = 0; j < 4; ++j) {
        #pragma unroll
        for (int mi = 0; mi < 8; ++mi) {
            int row = m0 + wmo + mi * 16 + row_l + j;
            float* orow = out + (size_t)row * 4096 + n0 + wno + rl;
            #pragma unroll
            for (int ni = 0; ni < 4; ++ni)
                orow[ni * 16] = acc[mi][ni][j] + bv[ni];
        }
    }
}

// ---------------------------------------------------------------------------
extern "C" void kernel_launch(void* const* d_in, const int* in_sizes, int n_in,
                              void* d_out, int out_size, void* d_ws, size_t ws_size,
                              hipStream_t stream) {
    const float* x    = (const float*)d_in[0];   // (4096, 4096)
    const float* Wc   = (const float*)d_in[1];   // (8, 512, 512)
    const float* bc   = (const float*)d_in[2];   // (8, 512)
    const float* Wf   = (const float*)d_in[3];   // (1024, 4096)
    const float* bfin = (const float*)d_in[4];   // (4096,)
    float* out = (float*)d_out;                  // (4096, 4096) fp32

    float* part = (float*)d_ws;                                    // 512 f32
    unsigned short* h   = (unsigned short*)((char*)d_ws + 4096);   // 4096x1024 bf16
    unsigned short* wct = h   + (size_t)4096 * 1024;               // 8x512x512 bf16
    unsigned short* wft = wct + (size_t)8 * 512 * 512;             // 4096x1024 bf16

    fused_prep_kernel<<<6656, 256, 0, stream>>>(x, Wc, Wf, part, wct, wft);
    gemm1_kernel<<<dim3(64, 4, 2), 256, 0, stream>>>(x, wct, bc, part, h);
    gemm2_kernel<<<dim3(16, 16, 1), 512, 0, stream>>>(h, wft, bfin, out);
}

// Round 11
// 183.100 us; speedup vs baseline: 1.1287x; 1.0122x over previous
//
#include <hip/hip_runtime.h>

// ---------------------------------------------------------------------------
// R15: write-path test + prep upgrade.
//  - gemm2: R7 K-loop verbatim (3 pipeline variants all = 43us -> schedule is
//    not the wall). NEW: epilogue relayouts C through LDS (reuse As/Bs 32KB)
//    so each wave stores 512B-contiguous segments (was 4x64B). Tests the
//    "write-path at ~1.5TB/s is the floor" hypothesis (WRITE/dur = 1.4-1.66
//    TB/s across ALL variants; R9's 16B-segment stores regressed to 48us).
//  - prep: transposes rebuilt at 64x64 tiles (read 256B/row, write 128B/row,
//    LDS [64][65] <=2-way banks). 6656 -> 2048 blocks.
//  - gemm1: R13 verbatim.
// ---------------------------------------------------------------------------

typedef __bf16 bf16x8_t __attribute__((ext_vector_type(8)));
typedef float  f32x4_t  __attribute__((ext_vector_type(4)));
typedef unsigned short u16x4 __attribute__((ext_vector_type(4)));

__device__ inline unsigned short f2bf(float f) {
    __bf16 b = (__bf16)f;
    return __builtin_bit_cast(unsigned short, b);
}

// async stage of 8 rows (wave-uniform row0) from bf16 global, 16 B/lane,
// XOR-swizzled granules: LDS slot gs holds global granule gs ^ (row & 7)
__device__ inline void stage_glds(const unsigned short* gtile, int stride, int row0,
                                  unsigned short* lds, int lane) {
    const int r8 = lane >> 3;
    const int gg = (lane & 7) ^ r8;
    const unsigned short* gp = gtile + (size_t)(row0 + r8) * stride + gg * 8;
    unsigned short* lp = lds + row0 * 64;
    __builtin_amdgcn_global_load_lds((const __attribute__((address_space(1))) void*)gp,
                                     (__attribute__((address_space(3))) void*)lp,
                                     16, 0, 0);
}

__device__ inline bf16x8_t ldsfrag(const unsigned short* Ls, int row, int kb) {
    return *(const bf16x8_t*)(Ls + row * 64 + (((kb >> 3) ^ (row & 7)) * 8));
}

// ---------------- K1: activity partials + 64x64 transposes -----------------
__global__ void fused_prep_kernel(const float* __restrict__ x, const float* __restrict__ Wc,
                                  const float* __restrict__ Wf, float* __restrict__ part,
                                  unsigned short* __restrict__ wct, unsigned short* __restrict__ wft) {
    const int b = blockIdx.x;
    const int tid = threadIdx.x;

    if (b < 512) {
        const int chunk = b & 7;
        const int rg = b >> 3;
        const int colf4 = tid & 127;
        const int rsub = tid >> 7;
        const float4* base = (const float4*)x + (size_t)chunk * 128 + colf4;
        float s = 0.f;
        #pragma unroll 4
        for (int i = 0; i < 32; ++i) {
            int row = rg * 64 + i * 2 + rsub;
            float4 v = base[(size_t)row * 1024];
            s += fabsf(v.x) + fabsf(v.y) + fabsf(v.z) + fabsf(v.w);
        }
        #pragma unroll
        for (int off = 32; off > 0; off >>= 1) s += __shfl_down(s, off, 64);
        __shared__ float wsum[4];
        if ((tid & 63) == 0) wsum[tid >> 6] = s;
        __syncthreads();
        if (tid == 0) part[chunk * 64 + rg] = wsum[0] + wsum[1] + wsum[2] + wsum[3];
        return;
    }

    // 64x64 fp32 transpose tile; read rows 256B-coalesced, write 128B/row.
    __shared__ float tile[64][65];
    const float* src; unsigned short* dst; int R, C, cb, rb;
    if (b < 1536) {                        // Wf^T: (1024,4096) -> (4096,1024)
        int jj = b - 512;                  // 16 x 64 tiles
        src = Wf; dst = wft; R = 1024; C = 4096;
        cb = (jj & 63) * 64; rb = (jj >> 6) * 64;
    } else {                               // Wc[c]^T for ALL c: 8 x (8x8 tiles)
        int jj = b - 1536;
        int c = jj >> 6, t = jj & 63;
        src = Wc + (size_t)c * 262144;
        dst = wct + (size_t)c * 262144;
        R = 512; C = 512;
        cb = (t & 7) * 64; rb = (t >> 3) * 64;
    }
    {
        const int cx = tid & 63;
        const int ry = tid >> 6;
        #pragma unroll
        for (int i = 0; i < 16; ++i)
            tile[ry + i * 4][cx] = src[(size_t)(rb + ry + i * 4) * C + cb + cx];
    }
    __syncthreads();
    {
        const int c16 = tid & 15;          // dst col group (4 ushorts)
        const int r16 = tid >> 4;          // dst row within 16-group
        #pragma unroll
        for (int p = 0; p < 4; ++p) {
            u16x4 hv;
            #pragma unroll
            for (int j = 0; j < 4; ++j) hv[j] = f2bf(tile[c16 * 4 + j][r16 + p * 16]);
            *(u16x4*)(dst + (size_t)(cb + r16 + p * 16) * R + rb + c16 * 4) = hv;
        }
    }
}

// ---------------- K2: GEMM1 — topk prologue + fused fp32 gather ------------
__global__ __launch_bounds__(256, 4)
void gemm1_kernel(const float* __restrict__ x, const unsigned short* __restrict__ wct,
                  const float* __restrict__ bc, const float* __restrict__ part,
                  unsigned short* __restrict__ h) {
    __shared__ __align__(16) unsigned char lds_raw[24576];
    unsigned short* As = (unsigned short*)lds_raw;            // 8 KB (64x64)
    unsigned short* Bs = (unsigned short*)(lds_raw + 8192);   // 16 KB (128x64)

    const int tid = threadIdx.x;
    const int wave = tid >> 6;
    const int lane = tid & 63;

    {
        float* sred = (float*)lds_raw;
        sred[tid] = part[tid];
        sred[tid + 256] = part[tid + 256];
        __syncthreads();
        float* act8 = (float*)(lds_raw + 2048);
        if (tid < 8) {
            float a = 0.f;
            #pragma unroll
            for (int k = 0; k < 64; ++k) a += sred[tid * 64 + k];
            act8[tid] = a;
        }
        __syncthreads();
    }
    int sel0, sel1;
    {
        const float* act8 = (const float*)(lds_raw + 2048);
        float v0 = -1e30f, v1 = -1e30f; int b0 = 0, b1 = 0;
        #pragma unroll
        for (int i = 0; i < 8; ++i) {
            float v = act8[i];
            if (v > v0) { v1 = v0; b1 = b0; v0 = v; b0 = i; }
            else if (v > v1) { v1 = v; b1 = i; }
        }
        sel0 = b0; sel1 = b1;
    }
    __syncthreads();

    const int z = blockIdx.z;
    const int idxz = z ? sel1 : sel0;
    const int m0 = blockIdx.x * 64;
    const int n0 = blockIdx.y * 128;
    const int wm = (wave >> 1) * 32;
    const int wn = (wave & 1) * 64;
    const int rl = lane & 15;
    const int quad = lane >> 4;

    const float* xtile = x + (size_t)m0 * 4096 + idxz * 512;
    const unsigned short* Btile = wct + (size_t)idxz * 262144 + (size_t)n0 * 512;

    f32x4_t acc[4][2] = {};   // [ni][mi] — operand-swapped mfma
    const int ar = tid >> 2;
    const int aq = tid & 3;

    for (int k0 = 0; k0 < 512; k0 += 64) {
        #pragma unroll
        for (int s = wave; s < 16; s += 4)
            stage_glds(Btile + k0, 512, s * 8, Bs, lane);
        const float* gr = xtile + (size_t)ar * 4096 + k0;
        #pragma unroll
        for (int j = 0; j < 2; ++j) {
            int gg = aq * 2 + j;
            float4 a = *(const float4*)(gr + gg * 8);
            float4 c = *(const float4*)(gr + gg * 8 + 4);
            bf16x8_t v;
            v[0] = (__bf16)a.x; v[1] = (__bf16)a.y; v[2] = (__bf16)a.z; v[3] = (__bf16)a.w;
            v[4] = (__bf16)c.x; v[5] = (__bf16)c.y; v[6] = (__bf16)c.z; v[7] = (__bf16)c.w;
            *(bf16x8_t*)(As + ar * 64 + ((gg ^ (ar & 7)) * 8)) = v;
        }
        __syncthreads();
        #pragma unroll
        for (int kq = 0; kq < 2; ++kq) {
            const int kb = kq * 32 + quad * 8;
            bf16x8_t af[2], bfr[4];
            #pragma unroll
            for (int i = 0; i < 2; ++i) af[i]  = ldsfrag(As, wm + i * 16 + rl, kb);
            #pragma unroll
            for (int i = 0; i < 4; ++i) bfr[i] = ldsfrag(Bs, wn + i * 16 + rl, kb);
            #pragma unroll
            for (int ni = 0; ni < 4; ++ni)
                #pragma unroll
                for (int mi = 0; mi < 2; ++mi)
                    acc[ni][mi] = __builtin_amdgcn_mfma_f32_16x16x32_bf16(bfr[ni], af[mi], acc[ni][mi], 0, 0, 0);
        }
        __syncthreads();
    }

    const float* bias = bc + (size_t)idxz * 512;
    #pragma unroll
    for (int ni = 0; ni < 4; ++ni) {
        const int colb = n0 + wn + ni * 16 + quad * 4;
        f32x4_t bv4 = *(const f32x4_t*)(bias + colb);
        #pragma unroll
        for (int mi = 0; mi < 2; ++mi) {
            int row = m0 + wm + mi * 16 + rl;
            f32x4_t o = acc[ni][mi] + bv4;
            u16x4 hv;
            #pragma unroll
            for (int j = 0; j < 4; ++j) hv[j] = f2bf(o[j]);
            *(u16x4*)(h + (size_t)row * 1024 + z * 512 + colb) = hv;
        }
    }
}

// ---------------- K3: GEMM2 — R7 K-loop + LDS-relayout 512B-seg epilogue ---
__global__ __launch_bounds__(256, 4)
void gemm2_kernel(const unsigned short* __restrict__ h, const unsigned short* __restrict__ wft,
                  const float* __restrict__ bfin, float* __restrict__ out) {
    __shared__ __align__(16) unsigned short AsBs[2 * 8192];   // As | Bs, 32 KB
    unsigned short* As = AsBs;
    unsigned short* Bs = AsBs + 8192;
    const int m0 = blockIdx.x * 128;
    const int n0 = blockIdx.y * 128;
    const int tid = threadIdx.x;
    const int wave = tid >> 6;
    const int lane = tid & 63;
    const int wm = (wave >> 1) * 64;
    const int wn = (wave & 1) * 64;
    const int rl = lane & 15;
    const int quad = lane >> 4;

    const unsigned short* Atile = h + (size_t)m0 * 1024;
    const unsigned short* Btile = wft + (size_t)n0 * 1024;

    f32x4_t acc[4][4] = {};

    for (int k0 = 0; k0 < 1024; k0 += 64) {
        #pragma unroll
        for (int s = wave; s < 32; s += 4) {
            if (s < 16) stage_glds(Atile + k0, 1024, s * 8, As, lane);
            else        stage_glds(Btile + k0, 1024, (s - 16) * 8, Bs, lane);
        }
        __syncthreads();
        #pragma unroll
        for (int kq = 0; kq < 2; ++kq) {
            const int kb = kq * 32 + quad * 8;
            bf16x8_t af[4], bfr[4];
            #pragma unroll
            for (int i = 0; i < 4; ++i) {
                af[i]  = ldsfrag(As, wm + i * 16 + rl, kb);
                bfr[i] = ldsfrag(Bs, wn + i * 16 + rl, kb);
            }
            #pragma unroll
            for (int mi = 0; mi < 4; ++mi)
                #pragma unroll
                for (int ni = 0; ni < 4; ++ni)
                    acc[mi][ni] = __builtin_amdgcn_mfma_f32_16x16x32_bf16(af[mi], bfr[ni], acc[mi][ni], 0, 0, 0);
        }
        __syncthreads();
    }

    // epilogue: relayout through LDS so stores are 512B-contiguous per wave.
    // ebuf = 64 rows x 128 cols fp32 (32 KB, reuses As|Bs). Two chunks.
    float* ebuf = (float*)AsBs;
    float bv[4];
    #pragma unroll
    for (int ni = 0; ni < 4; ++ni) bv[ni] = bfin[n0 + wn + ni * 16 + rl];

    #pragma unroll
    for (int c = 0; c < 2; ++c) {
        // waves {2c,2c+1} own rows 64c..64c+63; scatter acc (+bias) into ebuf
        if ((wave >> 1) == c) {
            #pragma unroll
            for (int mi = 0; mi < 4; ++mi)
                #pragma unroll
                for (int ni = 0; ni < 4; ++ni)
                    #pragma unroll
                    for (int j = 0; j < 4; ++j)
                        ebuf[(mi * 16 + quad * 4 + j) * 128 + wn + ni * 16 + rl]
                            = acc[mi][ni][j] + bv[ni];
        }
        __syncthreads();
        // all 256 threads stream ebuf out: 32 lanes x 16B = 512 B per row seg
        const int rr8 = tid >> 5;          // 0..7
        const int c4  = tid & 31;          // 0..31 col-float4
        #pragma unroll
        for (int i = 0; i < 8; ++i) {
            int rr = i * 8 + rr8;
            f32x4_t v = *(const f32x4_t*)(ebuf + rr * 128 + c4 * 4);
            *(f32x4_t*)(out + (size_t)(m0 + c * 64 + rr) * 4096 + n0 + c4 * 4) = v;
        }
        __syncthreads();                   // reads done before next chunk's writes
    }
}

// ---------------------------------------------------------------------------
extern "C" void kernel_launch(void* const* d_in, const int* in_sizes, int n_in,
                              void* d_out, int out_size, void* d_ws, size_t ws_size,
                              hipStream_t stream) {
    const float* x    = (const float*)d_in[0];   // (4096, 4096)
    const float* Wc   = (const float*)d_in[1];   // (8, 512, 512)
    const float* bc   = (const float*)d_in[2];   // (8, 512)
    const float* Wf   = (const float*)d_in[3];   // (1024, 4096)
    const float* bfin = (const float*)d_in[4];   // (4096,)
    float* out = (float*)d_out;                  // (4096, 4096) fp32

    float* part = (float*)d_ws;                                    // 512 f32
    unsigned short* h   = (unsigned short*)((char*)d_ws + 4096);   // 4096x1024 bf16
    unsigned short* wct = h   + (size_t)4096 * 1024;               // 8x512x512 bf16
    unsigned short* wft = wct + (size_t)8 * 512 * 512;             // 4096x1024 bf16

    fused_prep_kernel<<<2048, 256, 0, stream>>>(x, Wc, Wf, part, wct, wft);
    gemm1_kernel<<<dim3(64, 4, 2), 256, 0, stream>>>(x, wct, bc, part, h);
    gemm2_kernel<<<dim3(32, 32, 1), 256, 0, stream>>>(h, wft, bfin, out);
}

// Round 17
// 182.470 us; speedup vs baseline: 1.1326x; 1.0035x over previous
//
#include <hip/hip_runtime.h>

// ---------------------------------------------------------------------------
// R16 (resubmit x5 after broker timeouts): gemm2 -> fine-phase 256x256.
//  - BK=64, 512 thr / 8 waves (2Mx4N), per-wave 128x64 out, acc[8][4]
//  - LDS 128 KiB: 2 K-tile buffers x (A 256x64 + B 256x64)
//  - 4 phases per K-tile; per phase: {ds_read subtile + 1 half-tile stage
//    (2 glds) -> s_barrier -> lgkmcnt(0) -> setprio(1) -> 16 MFMA ->
//    setprio(0) -> barrier}; ONE vmcnt(4) per K-tile (counted, non-draining)
//  - half-tile stagger (provable): ph0/ph1 stage A(t+1) (A bufs swap);
//    ph2/ph3 stage B(t+2) (B(t)'s slot, freed after ph0). Gate at ph3
//    leaves exactly ph2+ph3 (4 loads) in flight.
//  - granule-XOR LDS swizzle pair carried from R7 (measured 0 conflicts)
// prep: R15 (64x64 transpose tiles). gemm1: R13. Epilogue: scalar j-outer
// (R15 proved epilogue off-critical-path).
// ---------------------------------------------------------------------------

typedef __bf16 bf16x8_t __attribute__((ext_vector_type(8)));
typedef float  f32x4_t  __attribute__((ext_vector_type(4)));
typedef unsigned short u16x4 __attribute__((ext_vector_type(4)));

__device__ inline unsigned short f2bf(float f) {
    __bf16 b = (__bf16)f;
    return __builtin_bit_cast(unsigned short, b);
}

// async stage of 8 rows (wave-uniform row0) from bf16 global, 16 B/lane,
// XOR-swizzled granules: LDS slot gs holds global granule gs ^ (row & 7)
__device__ inline void stage_glds(const unsigned short* gtile, int stride, int row0,
                                  unsigned short* lds, int lane) {
    const int r8 = lane >> 3;
    const int gg = (lane & 7) ^ r8;
    const unsigned short* gp = gtile + (size_t)(row0 + r8) * stride + gg * 8;
    unsigned short* lp = lds + row0 * 64;
    __builtin_amdgcn_global_load_lds((const __attribute__((address_space(1))) void*)gp,
                                     (__attribute__((address_space(3))) void*)lp,
                                     16, 0, 0);
}

__device__ inline bf16x8_t ldsfrag(const unsigned short* Ls, int row, int kb) {
    return *(const bf16x8_t*)(Ls + row * 64 + (((kb >> 3) ^ (row & 7)) * 8));
}

// stage one 128-row half (16 KB) of a BK=64 tile: 2 glds/thread across 8 waves
__device__ inline void stage_half(const unsigned short* ghalf, unsigned short* lhalf,
                                  int wv, int lane) {
    stage_glds(ghalf, 1024, wv * 8, lhalf, lane);
    stage_glds(ghalf, 1024, 64 + wv * 8, lhalf, lane);
}

// ---------------- K1: activity partials + 64x64 transposes -----------------
__global__ void fused_prep_kernel(const float* __restrict__ x, const float* __restrict__ Wc,
                                  const float* __restrict__ Wf, float* __restrict__ part,
                                  unsigned short* __restrict__ wct, unsigned short* __restrict__ wft) {
    const int b = blockIdx.x;
    const int tid = threadIdx.x;

    if (b < 512) {
        const int chunk = b & 7;
        const int rg = b >> 3;
        const int colf4 = tid & 127;
        const int rsub = tid >> 7;
        const float4* base = (const float4*)x + (size_t)chunk * 128 + colf4;
        float s = 0.f;
        #pragma unroll 4
        for (int i = 0; i < 32; ++i) {
            int row = rg * 64 + i * 2 + rsub;
            float4 v = base[(size_t)row * 1024];
            s += fabsf(v.x) + fabsf(v.y) + fabsf(v.z) + fabsf(v.w);
        }
        #pragma unroll
        for (int off = 32; off > 0; off >>= 1) s += __shfl_down(s, off, 64);
        __shared__ float wsum[4];
        if ((tid & 63) == 0) wsum[tid >> 6] = s;
        __syncthreads();
        if (tid == 0) part[chunk * 64 + rg] = wsum[0] + wsum[1] + wsum[2] + wsum[3];
        return;
    }

    __shared__ float tile[64][65];
    const float* src; unsigned short* dst; int R, C, cb, rb;
    if (b < 1536) {                        // Wf^T: (1024,4096) -> (4096,1024)
        int jj = b - 512;
        src = Wf; dst = wft; R = 1024; C = 4096;
        cb = (jj & 63) * 64; rb = (jj >> 6) * 64;
    } else {                               // Wc[c]^T for ALL c
        int jj = b - 1536;
        int c = jj >> 6, t = jj & 63;
        src = Wc + (size_t)c * 262144;
        dst = wct + (size_t)c * 262144;
        R = 512; C = 512;
        cb = (t & 7) * 64; rb = (t >> 3) * 64;
    }
    {
        const int cx = tid & 63;
        const int ry = tid >> 6;
        #pragma unroll
        for (int i = 0; i < 16; ++i)
            tile[ry + i * 4][cx] = src[(size_t)(rb + ry + i * 4) * C + cb + cx];
    }
    __syncthreads();
    {
        const int c16 = tid & 15;
        const int r16 = tid >> 4;
        #pragma unroll
        for (int p = 0; p < 4; ++p) {
            u16x4 hv;
            #pragma unroll
            for (int j = 0; j < 4; ++j) hv[j] = f2bf(tile[c16 * 4 + j][r16 + p * 16]);
            *(u16x4*)(dst + (size_t)(cb + r16 + p * 16) * R + rb + c16 * 4) = hv;
        }
    }
}

// ---------------- K2: GEMM1 — topk prologue + fused fp32 gather ------------
__global__ __launch_bounds__(256, 4)
void gemm1_kernel(const float* __restrict__ x, const unsigned short* __restrict__ wct,
                  const float* __restrict__ bc, const float* __restrict__ part,
                  unsigned short* __restrict__ h) {
    __shared__ __align__(16) unsigned char lds_raw[24576];
    unsigned short* As = (unsigned short*)lds_raw;            // 8 KB (64x64)
    unsigned short* Bs = (unsigned short*)(lds_raw + 8192);   // 16 KB (128x64)

    const int tid = threadIdx.x;
    const int wave = tid >> 6;
    const int lane = tid & 63;

    {
        float* sred = (float*)lds_raw;
        sred[tid] = part[tid];
        sred[tid + 256] = part[tid + 256];
        __syncthreads();
        float* act8 = (float*)(lds_raw + 2048);
        if (tid < 8) {
            float a = 0.f;
            #pragma unroll
            for (int k = 0; k < 64; ++k) a += sred[tid * 64 + k];
            act8[tid] = a;
        }
        __syncthreads();
    }
    int sel0, sel1;
    {
        const float* act8 = (const float*)(lds_raw + 2048);
        float v0 = -1e30f, v1 = -1e30f; int b0 = 0, b1 = 0;
        #pragma unroll
        for (int i = 0; i < 8; ++i) {
            float v = act8[i];
            if (v > v0) { v1 = v0; b1 = b0; v0 = v; b0 = i; }
            else if (v > v1) { v1 = v; b1 = i; }
        }
        sel0 = b0; sel1 = b1;
    }
    __syncthreads();

    const int z = blockIdx.z;
    const int idxz = z ? sel1 : sel0;
    const int m0 = blockIdx.x * 64;
    const int n0 = blockIdx.y * 128;
    const int wm = (wave >> 1) * 32;
    const int wn = (wave & 1) * 64;
    const int rl = lane & 15;
    const int quad = lane >> 4;

    const float* xtile = x + (size_t)m0 * 4096 + idxz * 512;
    const unsigned short* Btile = wct + (size_t)idxz * 262144 + (size_t)n0 * 512;

    f32x4_t acc[4][2] = {};   // [ni][mi] — operand-swapped mfma
    const int ar = tid >> 2;
    const int aq = tid & 3;

    for (int k0 = 0; k0 < 512; k0 += 64) {
        #pragma unroll
        for (int s = wave; s < 16; s += 4)
            stage_glds(Btile + k0, 512, s * 8, Bs, lane);
        const float* gr = xtile + (size_t)ar * 4096 + k0;
        #pragma unroll
        for (int j = 0; j < 2; ++j) {
            int gg = aq * 2 + j;
            float4 a = *(const float4*)(gr + gg * 8);
            float4 c = *(const float4*)(gr + gg * 8 + 4);
            bf16x8_t v;
            v[0] = (__bf16)a.x; v[1] = (__bf16)a.y; v[2] = (__bf16)a.z; v[3] = (__bf16)a.w;
            v[4] = (__bf16)c.x; v[5] = (__bf16)c.y; v[6] = (__bf16)c.z; v[7] = (__bf16)c.w;
            *(bf16x8_t*)(As + ar * 64 + ((gg ^ (ar & 7)) * 8)) = v;
        }
        __syncthreads();
        #pragma unroll
        for (int kq = 0; kq < 2; ++kq) {
            const int kb = kq * 32 + quad * 8;
            bf16x8_t af[2], bfr[4];
            #pragma unroll
            for (int i = 0; i < 2; ++i) af[i]  = ldsfrag(As, wm + i * 16 + rl, kb);
            #pragma unroll
            for (int i = 0; i < 4; ++i) bfr[i] = ldsfrag(Bs, wn + i * 16 + rl, kb);
            #pragma unroll
            for (int ni = 0; ni < 4; ++ni)
                #pragma unroll
                for (int mi = 0; mi < 2; ++mi)
                    acc[ni][mi] = __builtin_amdgcn_mfma_f32_16x16x32_bf16(bfr[ni], af[mi], acc[ni][mi], 0, 0, 0);
        }
        __syncthreads();
    }

    const float* bias = bc + (size_t)idxz * 512;
    #pragma unroll
    for (int ni = 0; ni < 4; ++ni) {
        const int colb = n0 + wn + ni * 16 + quad * 4;
        f32x4_t bv4 = *(const f32x4_t*)(bias + colb);
        #pragma unroll
        for (int mi = 0; mi < 2; ++mi) {
            int row = m0 + wm + mi * 16 + rl;
            f32x4_t o = acc[ni][mi] + bv4;
            u16x4 hv;
            #pragma unroll
            for (int j = 0; j < 4; ++j) hv[j] = f2bf(o[j]);
            *(u16x4*)(h + (size_t)row * 1024 + z * 512 + colb) = hv;
        }
    }
}

// ---------------- K3: GEMM2 — 256x256, 4-phase/K-tile, counted vmcnt -------
__global__ __launch_bounds__(512, 2)
void gemm2_kernel(const unsigned short* __restrict__ h, const unsigned short* __restrict__ wft,
                  const float* __restrict__ bfin, float* __restrict__ out) {
    // A bufs: [2] x 256x64 @ 0 / 16384 shorts; B bufs: @ 32768 / 49152
    __shared__ __align__(16) unsigned short lds_s[65536];   // 128 KiB

    const int tid  = threadIdx.x;
    const int wv   = tid >> 6;
    const int lane = tid & 63;
    const int m0 = blockIdx.x * 256;
    const int n0 = blockIdx.y * 256;
    const int wmo = (wv >> 2) * 128;      // 2 M-groups
    const int wno = (wv & 3) * 64;        // 4 N-groups
    const int rl   = lane & 15;
    const int quad = lane >> 4;

    const unsigned short* Atile = h   + (size_t)m0 * 1024;
    const unsigned short* Btile = wft + (size_t)n0 * 1024;

    f32x4_t acc[8][4] = {};

    // prologue: stage B(0), A(0), B(1) = 12 glds/thread; wait first 8
    stage_half(Btile,                          lds_s + 32768,        wv, lane);
    stage_half(Btile + (size_t)128 * 1024,     lds_s + 32768 + 8192, wv, lane);
    stage_half(Atile,                          lds_s,                wv, lane);
    stage_half(Atile + (size_t)128 * 1024,     lds_s + 8192,         wv, lane);
    stage_half(Btile + 64,                     lds_s + 49152,        wv, lane);
    stage_half(Btile + (size_t)128 * 1024 + 64, lds_s + 49152 + 8192, wv, lane);
    asm volatile("s_waitcnt vmcnt(4)" ::: "memory");
    __builtin_amdgcn_s_barrier();
    __builtin_amdgcn_sched_barrier(0);

    #pragma unroll 2
    for (int t = 0; t < 16; ++t) {
        const int bd = t & 1;
        const unsigned short* Acur = lds_s + bd * 16384;
        const unsigned short* Bcur = lds_s + 32768 + bd * 16384;
        const int ta = (t + 1 < 16) ? t + 1 : 15;   // A restage: dead slot
        const int tb = (t + 2 < 16) ? t + 2 : 15;   // B restage: dead/same-value
        unsigned short* Adst = lds_s + ((t + 1) & 1) * 16384;
        unsigned short* Bdst = lds_s + 32768 + bd * 16384;

        bf16x8_t bf[8];                    // B-frags live across the 4 phases
        #pragma unroll
        for (int ph = 0; ph < 4; ++ph) {
            bf16x8_t af[2][2];
            if (ph == 0) {
                #pragma unroll
                for (int ni = 0; ni < 4; ++ni)
                    #pragma unroll
                    for (int kq = 0; kq < 2; ++kq)
                        bf[ni * 2 + kq] = ldsfrag(Bcur, wno + ni * 16 + rl, kq * 32 + quad * 8);
            }
            #pragma unroll
            for (int mi = 0; mi < 2; ++mi)
                #pragma unroll
                for (int kq = 0; kq < 2; ++kq)
                    af[mi][kq] = ldsfrag(Acur, wmo + ph * 32 + mi * 16 + rl, kq * 32 + quad * 8);

            // stage one half-tile: ph0/ph1 -> A(t+1); ph2/ph3 -> B(t+2)
            if (ph == 0)      stage_half(Atile + ta * 64,                         Adst,        wv, lane);
            else if (ph == 1) stage_half(Atile + (size_t)128 * 1024 + ta * 64,    Adst + 8192, wv, lane);
            else if (ph == 2) stage_half(Btile + tb * 64,                         Bdst,        wv, lane);
            else              stage_half(Btile + (size_t)128 * 1024 + tb * 64,    Bdst + 8192, wv, lane);

            __builtin_amdgcn_sched_barrier(0);
            __builtin_amdgcn_s_barrier();
            asm volatile("s_waitcnt lgkmcnt(0)" ::: "memory");
            __builtin_amdgcn_sched_barrier(0);
            __builtin_amdgcn_s_setprio(1);
            #pragma unroll
            for (int mi = 0; mi < 2; ++mi)
                #pragma unroll
                for (int ni = 0; ni < 4; ++ni)
                    #pragma unroll
                    for (int kq = 0; kq < 2; ++kq)
                        acc[ph * 2 + mi][ni] = __builtin_amdgcn_mfma_f32_16x16x32_bf16(
                            af[mi][kq], bf[ni * 2 + kq], acc[ph * 2 + mi][ni], 0, 0, 0);
            __builtin_amdgcn_s_setprio(0);
            __builtin_amdgcn_sched_barrier(0);
            if (ph == 3) asm volatile("s_waitcnt vmcnt(4)" ::: "memory");
            __builtin_amdgcn_s_barrier();
            __builtin_amdgcn_sched_barrier(0);
        }
    }
    // drain dead tail restages before LDS lifetime ends
    asm volatile("s_waitcnt vmcnt(0)" ::: "memory");

    // epilogue: j-outer scalar stores (R7/R14-verified mapping; off crit path)
    const int row_l = quad * 4;
    float bv[4];
    #pragma unroll
    for (int ni = 0; ni < 4; ++ni) bv[ni] = bfin[n0 + wno + ni * 16 + rl];
    #pragma unroll
    for (int j = 0; j < 4; ++j) {
        #pragma unroll
        for (int MI = 0; MI < 8; ++MI) {
            int row = m0 + wmo + MI * 16 + row_l + j;
            float* orow = out + (size_t)row * 4096 + n0 + wno + rl;
            #pragma unroll
            for (int ni = 0; ni < 4; ++ni)
                orow[ni * 16] = acc[MI][ni][j] + bv[ni];
        }
    }
}

// ---------------------------------------------------------------------------
extern "C" void kernel_launch(void* const* d_in, const int* in_sizes, int n_in,
                              void* d_out, int out_size, void* d_ws, size_t ws_size,
                              hipStream_t stream) {
    const float* x    = (const float*)d_in[0];   // (4096, 4096)
    const float* Wc   = (const float*)d_in[1];   // (8, 512, 512)
    const float* bc   = (const float*)d_in[2];   // (8, 512)
    const float* Wf   = (const float*)d_in[3];   // (1024, 4096)
    const float* bfin = (const float*)d_in[4];   // (4096,)
    float* out = (float*)d_out;                  // (4096, 4096) fp32

    float* part = (float*)d_ws;                                    // 512 f32
    unsigned short* h   = (unsigned short*)((char*)d_ws + 4096);   // 4096x1024 bf16
    unsigned short* wct = h   + (size_t)4096 * 1024;               // 8x512x512 bf16
    unsigned short* wft = wct + (size_t)8 * 512 * 512;             // 4096x1024 bf16

    fused_prep_kernel<<<2048, 256, 0, stream>>>(x, Wc, Wf, part, wct, wft);
    gemm1_kernel<<<dim3(64, 4, 2), 256, 0, stream>>>(x, wct, bc, part, h);
    gemm2_kernel<<<dim3(16, 16, 1), 512, 0, stream>>>(h, wft, bfin, out);
}